// Round 1
// baseline (435.387 us; speedup 1.0000x reference)
//
#include <hip/hip_runtime.h>

#define D 128

// ---------------- CSR build ----------------

__global__ __launch_bounds__(256) void hist_kernel(const int* __restrict__ dst,
                                                   int* __restrict__ cnt, int E) {
    int i = blockIdx.x * 256 + threadIdx.x;
    if (i < E) atomicAdd(&cnt[dst[i]], 1);
}

__global__ __launch_bounds__(256) void scan_kernel(const int* __restrict__ cnt,
                                                   int* __restrict__ row_ptr,
                                                   int* __restrict__ cursor, int n) {
    __shared__ int part[256];
    int t = threadIdx.x;
    int chunk = (n + 255) >> 8;
    int beg = t * chunk;
    int end = min(beg + chunk, n);
    int s = 0;
    for (int i = beg; i < end; ++i) s += cnt[i];
    part[t] = s;
    __syncthreads();
    for (int off = 1; off < 256; off <<= 1) {
        int v = (t >= off) ? part[t - off] : 0;
        __syncthreads();
        part[t] += v;
        __syncthreads();
    }
    int run = (t == 0) ? 0 : part[t - 1];
    for (int i = beg; i < end; ++i) {
        row_ptr[i] = run;
        cursor[i]  = run;
        run += cnt[i];
    }
    if (t == 255) row_ptr[n] = run;
}

__global__ __launch_bounds__(256) void scatter_kernel(const int* __restrict__ src,
                                                      const int* __restrict__ dst,
                                                      const float* __restrict__ wself,
                                                      const float* __restrict__ wppi,
                                                      int* __restrict__ cursor,
                                                      int* __restrict__ src_g,
                                                      float* __restrict__ wsg,
                                                      float* __restrict__ wpg, int E) {
    int i = blockIdx.x * 256 + threadIdx.x;
    if (i < E) {
        int d = dst[i];
        int pos = atomicAdd(&cursor[d], 1);
        src_g[pos] = src[i];
        wsg[pos]   = wself[i];
        wpg[pos]   = wppi[i];
    }
}

// ---------------- fused dual aggregation (res + ppi), CSR gather ----------------
// One wave per dst node; lane owns channels 2*lane, 2*lane+1. No atomics.

__global__ __launch_bounds__(256) void agg_kernel(const float* __restrict__ h,
                                                  const int* __restrict__ row_ptr,
                                                  const int* __restrict__ src_g,
                                                  const float* __restrict__ wsg,
                                                  const float* __restrict__ wpg,
                                                  float* __restrict__ res,
                                                  float* __restrict__ ppi, int n) {
    int wid  = (blockIdx.x * 256 + threadIdx.x) >> 6;
    int lane = threadIdx.x & 63;
    if (wid >= n) return;
    int node = __builtin_amdgcn_readfirstlane(wid);
    int beg = row_ptr[node];
    int end = row_ptr[node + 1];
    float rx = 0.f, ry = 0.f, px = 0.f, py = 0.f;
    int e = beg;
    for (; e + 2 <= end; e += 2) {
        int   s0 = src_g[e],   s1 = src_g[e + 1];
        float a0 = wsg[e],     a1 = wsg[e + 1];
        float b0 = wpg[e],     b1 = wpg[e + 1];
        float2 h0 = *(const float2*)(h + (size_t)s0 * D + 2 * lane);
        float2 h1 = *(const float2*)(h + (size_t)s1 * D + 2 * lane);
        rx = fmaf(a0, h0.x, rx); ry = fmaf(a0, h0.y, ry);
        px = fmaf(b0, h0.x, px); py = fmaf(b0, h0.y, py);
        rx = fmaf(a1, h1.x, rx); ry = fmaf(a1, h1.y, ry);
        px = fmaf(b1, h1.x, px); py = fmaf(b1, h1.y, py);
    }
    if (e < end) {
        int   s0 = src_g[e];
        float a0 = wsg[e];
        float b0 = wpg[e];
        float2 h0 = *(const float2*)(h + (size_t)s0 * D + 2 * lane);
        rx = fmaf(a0, h0.x, rx); ry = fmaf(a0, h0.y, ry);
        px = fmaf(b0, h0.x, px); py = fmaf(b0, h0.y, py);
    }
    *(float2*)(res + (size_t)node * D + 2 * lane) = make_float2(rx, ry);
    *(float2*)(ppi + (size_t)node * D + 2 * lane) = make_float2(px, py);
}

// ---------------- node update: out = relu(ppi @ W^T + b) + res ----------------
// W^T staged in LDS (64 KB, 2 blocks/CU). Wave computes 4 nodes; lane owns
// outputs 2*lane, 2*lane+1; ppi[n][k] broadcast via v_readlane -> SGPR fma operand.

__global__ __launch_bounds__(256, 2) void update_kernel(const float* __restrict__ ppi,
                                                        const float* __restrict__ res,
                                                        const float* __restrict__ W,
                                                        const float* __restrict__ b,
                                                        float* __restrict__ hout, int n) {
    __shared__ float Wlds[D * D];  // Wlds[k*D + o] = W[o*D + k]
    int t = threadIdx.x;
    #pragma unroll
    for (int i = 0; i < (D * D) / 256; ++i) {
        int idx = i * 256 + t;
        int o = idx >> 7;
        int k = idx & 127;
        Wlds[k * D + o] = W[o * D + k];
    }
    __syncthreads();

    int w = t >> 6, lane = t & 63;
    float2 bb = *(const float2*)(b + 2 * lane);
    int gw = blockIdx.x * 4 + w;
    int nwaves = gridDim.x * 4;
    int ntiles = (n + 3) >> 2;
    for (int tile = gw; tile < ntiles; tile += nwaves) {
        int n0 = tile * 4;
        float2 pv[4];
        #pragma unroll
        for (int j = 0; j < 4; ++j) {
            if (n0 + j < n)
                pv[j] = *(const float2*)(ppi + (size_t)(n0 + j) * D + 2 * lane);
            else
                pv[j] = make_float2(0.f, 0.f);
        }
        float2 acc[4];
        #pragma unroll
        for (int j = 0; j < 4; ++j) acc[j] = make_float2(0.f, 0.f);

        #pragma unroll 4
        for (int m = 0; m < 64; ++m) {
            float2 w0 = *(const float2*)&Wlds[(2 * m) * D + 2 * lane];
            float2 w1 = *(const float2*)&Wlds[(2 * m + 1) * D + 2 * lane];
            #pragma unroll
            for (int j = 0; j < 4; ++j) {
                float pxv = __int_as_float(__builtin_amdgcn_readlane(__float_as_int(pv[j].x), m));
                float pyv = __int_as_float(__builtin_amdgcn_readlane(__float_as_int(pv[j].y), m));
                acc[j].x = fmaf(pxv, w0.x, acc[j].x);
                acc[j].y = fmaf(pxv, w0.y, acc[j].y);
                acc[j].x = fmaf(pyv, w1.x, acc[j].x);
                acc[j].y = fmaf(pyv, w1.y, acc[j].y);
            }
        }
        #pragma unroll
        for (int j = 0; j < 4; ++j) {
            if (n0 + j < n) {
                float2 rr = *(const float2*)(res + (size_t)(n0 + j) * D + 2 * lane);
                float2 o;
                o.x = fmaxf(acc[j].x + bb.x, 0.f) + rr.x;
                o.y = fmaxf(acc[j].y + bb.y, 0.f) + rr.y;
                *(float2*)(hout + (size_t)(n0 + j) * D + 2 * lane) = o;
            }
        }
    }
}

// ---------------- launch ----------------

extern "C" void kernel_launch(void* const* d_in, const int* in_sizes, int n_in,
                              void* d_out, int out_size, void* d_ws, size_t ws_size,
                              hipStream_t stream) {
    const float* h0    = (const float*)d_in[0];
    const int*   esrc  = (const int*)d_in[1];
    const int*   edst  = (const int*)d_in[2];
    const float* wself = (const float*)d_in[3];
    const float* wppi  = (const float*)d_in[4];
    const float* W     = (const float*)d_in[5];
    const float* b     = (const float*)d_in[6];
    float*       out   = (float*)d_out;

    const int N = in_sizes[0] / D;
    const int E = in_sizes[1];
    const int L = in_sizes[5] / (D * D);

    char* ws = (char*)d_ws;
    float* res    = (float*)ws; ws += (size_t)N * D * 4;
    float* ppi    = (float*)ws; ws += (size_t)N * D * 4;
    float* wsg    = (float*)ws; ws += (size_t)E * 4;
    float* wpg    = (float*)ws; ws += (size_t)E * 4;
    int* src_g    = (int*)ws;   ws += (size_t)E * 4;
    int* row_ptr  = (int*)ws;   ws += (size_t)(N + 1) * 4;
    int* cnt      = (int*)ws;   ws += (size_t)N * 4;
    int* cursor   = (int*)ws;   ws += (size_t)N * 4;

    hipMemsetAsync(cnt, 0, (size_t)N * 4, stream);
    int eb = (E + 255) / 256;
    hist_kernel<<<eb, 256, 0, stream>>>(edst, cnt, E);
    scan_kernel<<<1, 256, 0, stream>>>(cnt, row_ptr, cursor, N);
    scatter_kernel<<<eb, 256, 0, stream>>>(esrc, edst, wself, wppi, cursor, src_g, wsg, wpg, E);

    int ab = (N + 3) / 4;  // one wave per node, 4 waves/block
    const float* hin = h0;
    for (int l = 0; l < L; ++l) {
        agg_kernel<<<ab, 256, 0, stream>>>(hin, row_ptr, src_g, wsg, wpg, res, ppi, N);
        update_kernel<<<512, 256, 0, stream>>>(ppi, res, W + (size_t)l * D * D,
                                               b + (size_t)l * D, out, N);
        hin = out;
    }
}

// Round 2
// 350.937 us; speedup vs baseline: 1.2406x; 1.2406x over previous
//
#include <hip/hip_runtime.h>

#define D 128

// ---------------- CSR build ----------------

__global__ __launch_bounds__(256) void hist_kernel(const int* __restrict__ dst,
                                                   int* __restrict__ cnt, int E) {
    int i = blockIdx.x * 256 + threadIdx.x;
    if (i < E) atomicAdd(&cnt[dst[i]], 1);
}

// Parallel exclusive scan over cnt[0..n) -> row_ptr/cursor, 3 phases.
// Phase 1: per-block (1024 elems) sums.
__global__ __launch_bounds__(256) void scan_phase1(const int* __restrict__ cnt,
                                                   int* __restrict__ part, int n) {
    __shared__ int s[256];
    int t = threadIdx.x;
    int idx0 = blockIdx.x * 1024 + t * 4;
    int sum = 0;
    #pragma unroll
    for (int i = 0; i < 4; ++i) {
        int idx = idx0 + i;
        if (idx < n) sum += cnt[idx];
    }
    s[t] = sum;
    __syncthreads();
    // tree reduce
    for (int off = 128; off > 0; off >>= 1) {
        if (t < off) s[t] += s[t + off];
        __syncthreads();
    }
    if (t == 0) part[blockIdx.x] = s[0];
}

// Phase 2: scan the (<=256) block partials; also writes row_ptr[n] = total.
__global__ __launch_bounds__(256) void scan_phase2(int* __restrict__ part, int nparts,
                                                   int* __restrict__ row_ptr, int n) {
    __shared__ int s[256];
    int t = threadIdx.x;
    int v = (t < nparts) ? part[t] : 0;
    s[t] = v;
    __syncthreads();
    for (int off = 1; off < 256; off <<= 1) {
        int u = (t >= off) ? s[t - off] : 0;
        __syncthreads();
        s[t] += u;
        __syncthreads();
    }
    if (t < nparts) part[t] = s[t] - v;          // exclusive block offset
    if (t == nparts - 1) row_ptr[n] = s[t];      // grand total
}

// Phase 3: local prefix within each 1024-chunk + block offset -> row_ptr, cursor.
__global__ __launch_bounds__(256) void scan_phase3(const int* __restrict__ cnt,
                                                   const int* __restrict__ part,
                                                   int* __restrict__ row_ptr,
                                                   int* __restrict__ cursor, int n) {
    __shared__ int s[256];
    int t = threadIdx.x;
    int idx0 = blockIdx.x * 1024 + t * 4;
    int c[4];
    int sum = 0;
    #pragma unroll
    for (int i = 0; i < 4; ++i) {
        int idx = idx0 + i;
        c[i] = (idx < n) ? cnt[idx] : 0;
        sum += c[i];
    }
    s[t] = sum;
    __syncthreads();
    for (int off = 1; off < 256; off <<= 1) {
        int u = (t >= off) ? s[t - off] : 0;
        __syncthreads();
        s[t] += u;
        __syncthreads();
    }
    int run = part[blockIdx.x] + s[t] - sum;     // exclusive prefix for this thread
    #pragma unroll
    for (int i = 0; i < 4; ++i) {
        int idx = idx0 + i;
        if (idx < n) {
            row_ptr[idx] = run;
            cursor[idx]  = run;
            run += c[i];
        }
    }
}

__global__ __launch_bounds__(256) void scatter_kernel(const int* __restrict__ src,
                                                      const int* __restrict__ dst,
                                                      const float* __restrict__ wself,
                                                      const float* __restrict__ wppi,
                                                      int* __restrict__ cursor,
                                                      int* __restrict__ src_g,
                                                      float* __restrict__ wsg,
                                                      float* __restrict__ wpg, int E) {
    int i = blockIdx.x * 256 + threadIdx.x;
    if (i < E) {
        int d = dst[i];
        int pos = atomicAdd(&cursor[d], 1);
        src_g[pos] = src[i];
        wsg[pos]   = wself[i];
        wpg[pos]   = wppi[i];
    }
}

// ---------------- fused dual aggregation (res + ppi), CSR gather ----------------
// One wave per dst node; lane owns channels 2*lane, 2*lane+1. No atomics.

__global__ __launch_bounds__(256) void agg_kernel(const float* __restrict__ h,
                                                  const int* __restrict__ row_ptr,
                                                  const int* __restrict__ src_g,
                                                  const float* __restrict__ wsg,
                                                  const float* __restrict__ wpg,
                                                  float* __restrict__ res,
                                                  float* __restrict__ ppi, int n) {
    int wid  = (blockIdx.x * 256 + threadIdx.x) >> 6;
    int lane = threadIdx.x & 63;
    if (wid >= n) return;
    int node = __builtin_amdgcn_readfirstlane(wid);
    int beg = row_ptr[node];
    int end = row_ptr[node + 1];
    float rx = 0.f, ry = 0.f, px = 0.f, py = 0.f;
    int e = beg;
    for (; e + 2 <= end; e += 2) {
        int   s0 = src_g[e],   s1 = src_g[e + 1];
        float a0 = wsg[e],     a1 = wsg[e + 1];
        float b0 = wpg[e],     b1 = wpg[e + 1];
        float2 h0 = *(const float2*)(h + (size_t)s0 * D + 2 * lane);
        float2 h1 = *(const float2*)(h + (size_t)s1 * D + 2 * lane);
        rx = fmaf(a0, h0.x, rx); ry = fmaf(a0, h0.y, ry);
        px = fmaf(b0, h0.x, px); py = fmaf(b0, h0.y, py);
        rx = fmaf(a1, h1.x, rx); ry = fmaf(a1, h1.y, ry);
        px = fmaf(b1, h1.x, px); py = fmaf(b1, h1.y, py);
    }
    if (e < end) {
        int   s0 = src_g[e];
        float a0 = wsg[e];
        float b0 = wpg[e];
        float2 h0 = *(const float2*)(h + (size_t)s0 * D + 2 * lane);
        rx = fmaf(a0, h0.x, rx); ry = fmaf(a0, h0.y, ry);
        px = fmaf(b0, h0.x, px); py = fmaf(b0, h0.y, py);
    }
    *(float2*)(res + (size_t)node * D + 2 * lane) = make_float2(rx, ry);
    *(float2*)(ppi + (size_t)node * D + 2 * lane) = make_float2(px, py);
}

// ---------------- node update: out = relu(ppi @ W^T + b) + res ----------------
// W^T staged in LDS (64 KB, 2 blocks/CU). Wave computes 4 nodes; lane owns
// outputs 2*lane, 2*lane+1; ppi[n][k] broadcast via v_readlane -> SGPR fma operand.

__global__ __launch_bounds__(256, 2) void update_kernel(const float* __restrict__ ppi,
                                                        const float* __restrict__ res,
                                                        const float* __restrict__ W,
                                                        const float* __restrict__ b,
                                                        float* __restrict__ hout, int n) {
    __shared__ float Wlds[D * D];  // Wlds[k*D + o] = W[o*D + k]
    int t = threadIdx.x;
    #pragma unroll
    for (int i = 0; i < (D * D) / 256; ++i) {
        int idx = i * 256 + t;
        int o = idx >> 7;
        int k = idx & 127;
        Wlds[k * D + o] = W[o * D + k];
    }
    __syncthreads();

    int w = t >> 6, lane = t & 63;
    float2 bb = *(const float2*)(b + 2 * lane);
    int gw = blockIdx.x * 4 + w;
    int nwaves = gridDim.x * 4;
    int ntiles = (n + 3) >> 2;
    for (int tile = gw; tile < ntiles; tile += nwaves) {
        int n0 = tile * 4;
        float2 pv[4];
        #pragma unroll
        for (int j = 0; j < 4; ++j) {
            if (n0 + j < n)
                pv[j] = *(const float2*)(ppi + (size_t)(n0 + j) * D + 2 * lane);
            else
                pv[j] = make_float2(0.f, 0.f);
        }
        float2 acc[4];
        #pragma unroll
        for (int j = 0; j < 4; ++j) acc[j] = make_float2(0.f, 0.f);

        #pragma unroll 4
        for (int m = 0; m < 64; ++m) {
            float2 w0 = *(const float2*)&Wlds[(2 * m) * D + 2 * lane];
            float2 w1 = *(const float2*)&Wlds[(2 * m + 1) * D + 2 * lane];
            #pragma unroll
            for (int j = 0; j < 4; ++j) {
                float pxv = __int_as_float(__builtin_amdgcn_readlane(__float_as_int(pv[j].x), m));
                float pyv = __int_as_float(__builtin_amdgcn_readlane(__float_as_int(pv[j].y), m));
                acc[j].x = fmaf(pxv, w0.x, acc[j].x);
                acc[j].y = fmaf(pxv, w0.y, acc[j].y);
                acc[j].x = fmaf(pyv, w1.x, acc[j].x);
                acc[j].y = fmaf(pyv, w1.y, acc[j].y);
            }
        }
        #pragma unroll
        for (int j = 0; j < 4; ++j) {
            if (n0 + j < n) {
                float2 rr = *(const float2*)(res + (size_t)(n0 + j) * D + 2 * lane);
                float2 o;
                o.x = fmaxf(acc[j].x + bb.x, 0.f) + rr.x;
                o.y = fmaxf(acc[j].y + bb.y, 0.f) + rr.y;
                *(float2*)(hout + (size_t)(n0 + j) * D + 2 * lane) = o;
            }
        }
    }
}

// ---------------- launch ----------------

extern "C" void kernel_launch(void* const* d_in, const int* in_sizes, int n_in,
                              void* d_out, int out_size, void* d_ws, size_t ws_size,
                              hipStream_t stream) {
    const float* h0    = (const float*)d_in[0];
    const int*   esrc  = (const int*)d_in[1];
    const int*   edst  = (const int*)d_in[2];
    const float* wself = (const float*)d_in[3];
    const float* wppi  = (const float*)d_in[4];
    const float* W     = (const float*)d_in[5];
    const float* b     = (const float*)d_in[6];
    float*       out   = (float*)d_out;

    const int N = in_sizes[0] / D;
    const int E = in_sizes[1];
    const int L = in_sizes[5] / (D * D);

    char* ws = (char*)d_ws;
    float* res    = (float*)ws; ws += (size_t)N * D * 4;
    float* ppi    = (float*)ws; ws += (size_t)N * D * 4;
    float* wsg    = (float*)ws; ws += (size_t)E * 4;
    float* wpg    = (float*)ws; ws += (size_t)E * 4;
    int* src_g    = (int*)ws;   ws += (size_t)E * 4;
    int* row_ptr  = (int*)ws;   ws += (size_t)(N + 1) * 4;
    int* cnt      = (int*)ws;   ws += (size_t)N * 4;
    int* cursor   = (int*)ws;   ws += (size_t)N * 4;
    int* part     = (int*)ws;   ws += (size_t)256 * 4;

    hipMemsetAsync(cnt, 0, (size_t)N * 4, stream);
    int eb = (E + 255) / 256;
    hist_kernel<<<eb, 256, 0, stream>>>(edst, cnt, E);

    int nparts = (N + 1023) / 1024;   // 40 for N=40000 (<=256 supported)
    scan_phase1<<<nparts, 256, 0, stream>>>(cnt, part, N);
    scan_phase2<<<1, 256, 0, stream>>>(part, nparts, row_ptr, N);
    scan_phase3<<<nparts, 256, 0, stream>>>(cnt, part, row_ptr, cursor, N);

    scatter_kernel<<<eb, 256, 0, stream>>>(esrc, edst, wself, wppi, cursor, src_g, wsg, wpg, E);

    int ab = (N + 3) / 4;  // one wave per node, 4 waves/block
    const float* hin = h0;
    for (int l = 0; l < L; ++l) {
        agg_kernel<<<ab, 256, 0, stream>>>(hin, row_ptr, src_g, wsg, wpg, res, ppi, N);
        update_kernel<<<512, 256, 0, stream>>>(ppi, res, W + (size_t)l * D * D,
                                               b + (size_t)l * D, out, N);
        hin = out;
    }
}

// Round 3
// 277.576 us; speedup vs baseline: 1.5685x; 1.2643x over previous
//
#include <hip/hip_runtime.h>

#define D 128

typedef short bf16x8 __attribute__((ext_vector_type(8)));
typedef float f32x4  __attribute__((ext_vector_type(4)));

static __device__ __forceinline__ unsigned f2bf(float x) {
    unsigned u = __float_as_uint(x);
    return (u + 0x7FFFu + ((u >> 16) & 1u)) >> 16;   // RNE
}

// ---------------- f32 -> bf16 convert (vectorized x4) ----------------
__global__ __launch_bounds__(256) void cvt_bf16_kernel(const float4* __restrict__ in,
                                                       uint2* __restrict__ out, int n4) {
    int i = blockIdx.x * 256 + threadIdx.x;
    if (i < n4) {
        float4 v = in[i];
        uint2 o;
        o.x = f2bf(v.x) | (f2bf(v.y) << 16);
        o.y = f2bf(v.z) | (f2bf(v.w) << 16);
        out[i] = o;
    }
}

// ---------------- CSR build ----------------
__global__ __launch_bounds__(256) void hist_kernel(const int* __restrict__ dst,
                                                   int* __restrict__ cnt, int E) {
    int i = blockIdx.x * 256 + threadIdx.x;
    if (i < E) atomicAdd(&cnt[dst[i]], 1);
}

__global__ __launch_bounds__(256) void scan_phase1(const int* __restrict__ cnt,
                                                   int* __restrict__ part, int n) {
    __shared__ int s[256];
    int t = threadIdx.x;
    int idx0 = blockIdx.x * 1024 + t * 4;
    int sum = 0;
    #pragma unroll
    for (int i = 0; i < 4; ++i) {
        int idx = idx0 + i;
        if (idx < n) sum += cnt[idx];
    }
    s[t] = sum;
    __syncthreads();
    for (int off = 128; off > 0; off >>= 1) {
        if (t < off) s[t] += s[t + off];
        __syncthreads();
    }
    if (t == 0) part[blockIdx.x] = s[0];
}

__global__ __launch_bounds__(256) void scan_phase2(int* __restrict__ part, int nparts,
                                                   int* __restrict__ row_ptr, int n) {
    __shared__ int s[256];
    int t = threadIdx.x;
    int v = (t < nparts) ? part[t] : 0;
    s[t] = v;
    __syncthreads();
    for (int off = 1; off < 256; off <<= 1) {
        int u = (t >= off) ? s[t - off] : 0;
        __syncthreads();
        s[t] += u;
        __syncthreads();
    }
    if (t < nparts) part[t] = s[t] - v;
    if (t == nparts - 1) row_ptr[n] = s[t];
}

__global__ __launch_bounds__(256) void scan_phase3(const int* __restrict__ cnt,
                                                   const int* __restrict__ part,
                                                   int* __restrict__ row_ptr,
                                                   int* __restrict__ cursor, int n) {
    __shared__ int s[256];
    int t = threadIdx.x;
    int idx0 = blockIdx.x * 1024 + t * 4;
    int c[4];
    int sum = 0;
    #pragma unroll
    for (int i = 0; i < 4; ++i) {
        int idx = idx0 + i;
        c[i] = (idx < n) ? cnt[idx] : 0;
        sum += c[i];
    }
    s[t] = sum;
    __syncthreads();
    for (int off = 1; off < 256; off <<= 1) {
        int u = (t >= off) ? s[t - off] : 0;
        __syncthreads();
        s[t] += u;
        __syncthreads();
    }
    int run = part[blockIdx.x] + s[t] - sum;
    #pragma unroll
    for (int i = 0; i < 4; ++i) {
        int idx = idx0 + i;
        if (idx < n) {
            row_ptr[idx] = run;
            cursor[idx]  = run;
            run += c[i];
        }
    }
}

// Scatter into packed 16B edge records: {src, w_self bits, w_ppi bits, pad}
__global__ __launch_bounds__(256) void scatter_kernel(const int* __restrict__ src,
                                                      const int* __restrict__ dst,
                                                      const float* __restrict__ wself,
                                                      const float* __restrict__ wppi,
                                                      int* __restrict__ cursor,
                                                      int4* __restrict__ edges, int E) {
    int i = blockIdx.x * 256 + threadIdx.x;
    if (i < E) {
        int d = dst[i];
        int pos = atomicAdd(&cursor[d], 1);
        int4 e;
        e.x = src[i];
        e.y = __float_as_int(wself[i]);
        e.z = __float_as_int(wppi[i]);
        e.w = 0;
        edges[pos] = e;
    }
}

// ---------------- fused dual aggregation (res f32 + ppi bf16), bf16 gather ----------------
// One wave per dst node; lane owns channels 2*lane, 2*lane+1.
__global__ __launch_bounds__(256) void agg_kernel(const unsigned short* __restrict__ h16,
                                                  const int* __restrict__ row_ptr,
                                                  const int4* __restrict__ edges,
                                                  float* __restrict__ res,
                                                  unsigned int* __restrict__ ppi16, int n) {
    int wid  = (blockIdx.x * 256 + threadIdx.x) >> 6;
    int lane = threadIdx.x & 63;
    if (wid >= n) return;
    int node = __builtin_amdgcn_readfirstlane(wid);
    int beg = row_ptr[node];
    int end = row_ptr[node + 1];
    float rx = 0.f, ry = 0.f, px = 0.f, py = 0.f;
    int e = beg;
    for (; e + 2 <= end; e += 2) {
        int4 e0 = edges[e];
        int4 e1 = edges[e + 1];
        unsigned hv0 = *(const unsigned*)(h16 + (size_t)e0.x * D + 2 * lane);
        unsigned hv1 = *(const unsigned*)(h16 + (size_t)e1.x * D + 2 * lane);
        float a0 = __int_as_float(e0.y), b0 = __int_as_float(e0.z);
        float a1 = __int_as_float(e1.y), b1 = __int_as_float(e1.z);
        float h0x = __uint_as_float(hv0 << 16), h0y = __uint_as_float(hv0 & 0xFFFF0000u);
        float h1x = __uint_as_float(hv1 << 16), h1y = __uint_as_float(hv1 & 0xFFFF0000u);
        rx = fmaf(a0, h0x, rx); ry = fmaf(a0, h0y, ry);
        px = fmaf(b0, h0x, px); py = fmaf(b0, h0y, py);
        rx = fmaf(a1, h1x, rx); ry = fmaf(a1, h1y, ry);
        px = fmaf(b1, h1x, px); py = fmaf(b1, h1y, py);
    }
    if (e < end) {
        int4 e0 = edges[e];
        unsigned hv0 = *(const unsigned*)(h16 + (size_t)e0.x * D + 2 * lane);
        float a0 = __int_as_float(e0.y), b0 = __int_as_float(e0.z);
        float h0x = __uint_as_float(hv0 << 16), h0y = __uint_as_float(hv0 & 0xFFFF0000u);
        rx = fmaf(a0, h0x, rx); ry = fmaf(a0, h0y, ry);
        px = fmaf(b0, h0x, px); py = fmaf(b0, h0y, py);
    }
    *(float2*)(res + (size_t)node * D + 2 * lane) = make_float2(rx, ry);
    ppi16[(size_t)node * (D / 2) + lane] = f2bf(px) | (f2bf(py) << 16);
}

// ---------------- node update via bf16 MFMA: out = relu(ppi @ W^T + b) + res ----------------
// Wave computes a 16-node tile across all 128 outputs (8 o-tiles, K=128 -> 4 MFMA each).
// A frag: ppi16[n0 + (lane&15)][ (lane>>4)*8 + kt*32 .. +7 ]  (16B contiguous)
// B frag: Wb[o_tile*16 + (lane&15)][ same k slice ]            (16B contiguous)
// C/D: col(o) = lane&15, row(node) = (lane>>4)*4 + reg   [verified m89/m91]
__global__ __launch_bounds__(256) void update_mfma(const unsigned short* __restrict__ ppi16,
                                                   const float* __restrict__ res,
                                                   const unsigned short* __restrict__ Wb,
                                                   const float* __restrict__ bias,
                                                   float* __restrict__ out,
                                                   unsigned short* __restrict__ out16, int n) {
    int t = threadIdx.x;
    int wave = t >> 6, lane = t & 63;
    int m16 = lane & 15, quad = lane >> 4;
    int ntiles = n >> 4;                 // n divisible by 16
    int tile = blockIdx.x * 4 + wave;
    if (tile >= ntiles) return;
    int n0 = tile * 16;

    bf16x8 a[4];
    const unsigned short* arow = ppi16 + (size_t)(n0 + m16) * D + quad * 8;
    #pragma unroll
    for (int kt = 0; kt < 4; ++kt) a[kt] = *(const bf16x8*)(arow + kt * 32);

    #pragma unroll
    for (int ot = 0; ot < 8; ++ot) {
        const unsigned short* brow = Wb + (size_t)(ot * 16 + m16) * D + quad * 8;
        bf16x8 bfr[4];
        #pragma unroll
        for (int kt = 0; kt < 4; ++kt) bfr[kt] = *(const bf16x8*)(brow + kt * 32);
        f32x4 acc = {0.f, 0.f, 0.f, 0.f};
        #pragma unroll
        for (int kt = 0; kt < 4; ++kt)
            acc = __builtin_amdgcn_mfma_f32_16x16x32_bf16(a[kt], bfr[kt], acc, 0, 0, 0);

        int o = ot * 16 + m16;
        float bb = bias[o];
        #pragma unroll
        for (int r = 0; r < 4; ++r) {
            int node = n0 + quad * 4 + r;
            float v = fmaxf(acc[r] + bb, 0.f) + res[(size_t)node * D + o];
            out[(size_t)node * D + o] = v;
            if (out16) out16[(size_t)node * D + o] = (unsigned short)f2bf(v);
        }
    }
}

// ---------------- launch ----------------
extern "C" void kernel_launch(void* const* d_in, const int* in_sizes, int n_in,
                              void* d_out, int out_size, void* d_ws, size_t ws_size,
                              hipStream_t stream) {
    const float* h0    = (const float*)d_in[0];
    const int*   esrc  = (const int*)d_in[1];
    const int*   edst  = (const int*)d_in[2];
    const float* wself = (const float*)d_in[3];
    const float* wppi  = (const float*)d_in[4];
    const float* W     = (const float*)d_in[5];
    const float* b     = (const float*)d_in[6];
    float*       out   = (float*)d_out;

    const int N = in_sizes[0] / D;
    const int E = in_sizes[1];
    const int L = in_sizes[5] / (D * D);

    char* ws = (char*)d_ws;
    float*          res    = (float*)ws;          ws += (size_t)N * D * 4;   // 20.48 MB
    unsigned short* ppi16  = (unsigned short*)ws; ws += (size_t)N * D * 2;   // 10.24 MB
    unsigned short* h16    = (unsigned short*)ws; ws += (size_t)N * D * 2;   // 10.24 MB (reused as out16)
    int4*           edges  = (int4*)ws;           ws += (size_t)E * 16;      // 10.24 MB
    unsigned short* Wb     = (unsigned short*)ws; ws += (size_t)L * D * D * 2;
    int* row_ptr = (int*)ws;  ws += (size_t)(N + 1) * 4;
    int* cnt     = (int*)ws;  ws += (size_t)N * 4;
    int* cursor  = (int*)ws;  ws += (size_t)N * 4;
    int* part    = (int*)ws;  ws += (size_t)256 * 4;

    // bf16 copies of h0 and W
    int n4h = N * D / 4;
    cvt_bf16_kernel<<<(n4h + 255) / 256, 256, 0, stream>>>((const float4*)h0, (uint2*)h16, n4h);
    int n4w = L * D * D / 4;
    cvt_bf16_kernel<<<(n4w + 255) / 256, 256, 0, stream>>>((const float4*)W, (uint2*)Wb, n4w);

    hipMemsetAsync(cnt, 0, (size_t)N * 4, stream);
    int eb = (E + 255) / 256;
    hist_kernel<<<eb, 256, 0, stream>>>(edst, cnt, E);

    int nparts = (N + 1023) / 1024;
    scan_phase1<<<nparts, 256, 0, stream>>>(cnt, part, N);
    scan_phase2<<<1, 256, 0, stream>>>(part, nparts, row_ptr, N);
    scan_phase3<<<nparts, 256, 0, stream>>>(cnt, part, row_ptr, cursor, N);

    scatter_kernel<<<eb, 256, 0, stream>>>(esrc, edst, wself, wppi, cursor, edges, E);

    int ab = (N + 3) / 4;           // one wave per node
    int ub = (N / 16 + 3) / 4;      // one wave per 16-node tile
    const unsigned short* hin = h16;
    for (int l = 0; l < L; ++l) {
        agg_kernel<<<ab, 256, 0, stream>>>(hin, row_ptr, edges, res, (unsigned int*)ppi16, N);
        // layer l update: write f32 out; also bf16 copy into h16 buffer for next layer's gather
        unsigned short* o16 = (l + 1 < L) ? h16 : (unsigned short*)nullptr;
        update_mfma<<<ub, 256, 0, stream>>>(ppi16, res, Wb + (size_t)l * D * D,
                                            b + (size_t)l * D, out, o16, N);
        hin = h16;
    }
}